// Round 12
// baseline (129.954 us; speedup 1.0000x reference)
//
#include <hip/hip_runtime.h>
#include <math.h>

// EvidNets R25: 512 blocks x 512 thr, 2 blocks/CU (4 waves/SIMD), 32 samples
// x ALL 512 protos per block, 64KB aliased LDS pool. Two dispatches.
//   A_c(b) = prod_k (1 - s_kb*(1-U_kc)),  N(b) = prod_k (1 - s_kb)
//   out[b][c<20] = (A_c-N)/K, out[b][20] = N/K, K = sum_c A_c - 19N
//   s_kb = alphap_k * exp(-gamma_k^2*(0.5*(|W_k|^2+|x_b|^2) - W_k.x_b))
// R23/R24 post-mortem: 1024-thr blocks are DEAD on this toolchain -- three
// knobs (waves_per_eu x2, launch_bounds min-waves) all left a 64-VGPR cap
// with ~80MB spill traffic. 512-thr blocks allocate properly (R18b 76,
// R21 124). Round-0's gemm_comb proved 2 blocks/CU + aliased 64KB pool +
// one lockstep barrier runs ~30-35us (other block fills the bubble).
// R25 = that shape, made self-sufficient: 32 samples x 512 protos ->
// full product in-block, OUT in-block, no PP/finish/fences.
//  - wave wv: tiles 2wv,2wv+1 (96 MFMA); B2 barrier; swizzled s-bands;
//    B3; FULL-lane combine: lane=(sample pl, band h -> tile 2wv+h),
//    672 fma/lane (= round-0), shfl_xor(32) merge.
//  - VS: h-dependent base kills wave-uniform s_load, LDS is full ->
//    prep emits TRANSPOSED padded VST[512][24]; combine streams 6xfloat4
//    per proto (half-wave-broadcast L1 hits) into 21 running products.
// LDS 64.2KB: A 32K aliased under sc[32][512] 64K + xqs; endgame aliases.
// NOTE: plain __launch_bounds__(512) (min-waves args spilled, R4/R8).

#define NBATCH 16384
#define ND     256
#define NP     512
#define NCLS   20
#define OC     21
#define VSTW   24                       // padded VST row width (floats)

typedef short  short8  __attribute__((ext_vector_type(8)));
typedef short  short4v __attribute__((ext_vector_type(4)));
typedef unsigned short ushort8 __attribute__((ext_vector_type(8)));
typedef float  f32x16  __attribute__((ext_vector_type(16)));

// ---- workspace layout (bytes) ----
#define OFF_PWH 0u
#define OFF_PWL 262144u
#define OFF_VST 524288u                 // float VST[512][24]: [p][c]=1-U, [p][20]=1
#define OFF_WQ  573440u
#define OFF_AP  575488u
#define OFF_G2  577536u

__device__ __forceinline__ unsigned short f2bf_rn(float f) {
  unsigned int u = __float_as_uint(f);
  unsigned int r = (u + 0x7FFFu + ((u >> 16) & 1u)) >> 16;   // RNE (finite inputs)
  return (unsigned short)r;
}
__device__ __forceinline__ float bf2f(unsigned short h) {
  return __uint_as_float(((unsigned int)h) << 16);
}

// Combined prep: blocks 0..63 pack W[512][256] -> MFMA B-fragment order hi/lo
// bf16 + row sum-squares; blocks 64..65 build VST/AP/G2 tables.
// frag elem (tile,step,lane,j) = src[tile*32+(lane&31)][step*16+8*(lane>>5)+j]
__global__ __launch_bounds__(256)
void prep(const float* __restrict__ Wsrc, const float* __restrict__ BETA,
          const float* __restrict__ alpha, const float* __restrict__ gamma,
          unsigned short* __restrict__ dh, unsigned short* __restrict__ dl,
          float* __restrict__ sq, float* __restrict__ VST,
          float* __restrict__ AP, float* __restrict__ G2)
{
  const int bid = blockIdx.x;
  if (bid < 64) {                      // ---- pack W ----
    const int tid = bid * 256 + threadIdx.x;
    const int row = tid >> 5, seg = tid & 31;
    const float4* s4 = (const float4*)(Wsrc + (size_t)row * ND + seg * 8);
    const float4 a = s4[0], b = s4[1];
    const float v[8] = {a.x, a.y, a.z, a.w, b.x, b.y, b.z, b.w};
    ushort8 hv, lv;
    float ssq = 0.f;
    #pragma unroll
    for (int j = 0; j < 8; ++j) {
      ssq = fmaf(v[j], v[j], ssq);
      const unsigned short hh = f2bf_rn(v[j]);
      hv[j] = hh;
      lv[j] = f2bf_rn(v[j] - bf2f(hh));
    }
    const int tile = row >> 5, m = row & 31, step = seg >> 1, r = seg & 1;
    const size_t cidx = (size_t)(tile * 16 + step) * 64 + m + 32 * r;
    *(ushort8*)(dh + cidx * 8) = hv;
    *(ushort8*)(dl + cidx * 8) = lv;
    #pragma unroll
    for (int off = 1; off < 32; off <<= 1) ssq += __shfl_xor(ssq, off, 64);
    if (seg == 0) sq[row] = ssq;
  } else {                             // ---- scalar tables ----
    const int k = (bid - 64) * 256 + threadIdx.x;
    if (k >= NP) return;
    float bv[NCLS], bs = 0.f;
    #pragma unroll
    for (int c = 0; c < NCLS; ++c) { bv[c] = BETA[k * NCLS + c]; bs = fmaf(bv[c], bv[c], bs); }
    const float binv = 1.f / bs;
    float* vr = VST + k * VSTW;        // transposed row: all classes of proto k
    #pragma unroll
    for (int c = 0; c < NCLS; ++c) vr[c] = 1.f - bv[c] * bv[c] * binv;
    vr[NCLS] = 1.0f;                   // class 20: U-row == 0 -> VS == 1
    vr[21] = 0.f; vr[22] = 0.f; vr[23] = 0.f;   // padding
    AP[k] = 0.99f / (1.f + __expf(-alpha[k]));
    const float g = gamma[k];
    G2[k] = g * g;
  }
}

// One MFMA pass: the block's single 32-sample A-tile vs one 32-proto B-tile.
// K=256, hi/lo split in TWO acc chains (accA = ah*bh; accB = ah*bl + al*bh),
// depth-4 B ring, epilogue s -> sout[16]. (R18b-proven body.)
__device__ __forceinline__ void mfma_pass(
    const short* __restrict__ Ah, const short* __restrict__ Al,
    const short8* __restrict__ bHc, const short8* __restrict__ bLc,
    const int lane, const float* __restrict__ xqs,
    const float wqk, const float apk, const float g2k, float* __restrict__ sout)
{
  short8 wbh[4], wbl[4];
  #pragma unroll
  for (int p = 0; p < 4; ++p) { wbh[p] = bHc[p * 64]; wbl[p] = bLc[p * 64]; }

  f32x16 accA, accB;
  #pragma unroll
  for (int i = 0; i < 16; ++i) { accA[i] = 0.f; accB[i] = 0.f; }
  const short8* aH = (const short8*)Ah + lane;
  const short8* aL = (const short8*)Al + lane;
  #pragma unroll
  for (int step = 0; step < 16; ++step) {
    const short8 ah = aH[step * 64], al = aL[step * 64];
    const short8 bh = wbh[step & 3], bl = wbl[step & 3];
    if (step < 12) {
      wbh[step & 3] = bHc[(step + 4) * 64];
      wbl[step & 3] = bLc[(step + 4) * 64];
    }
    accA = __builtin_amdgcn_mfma_f32_32x32x16_bf16(ah, bh, accA, 0, 0, 0);
    accB = __builtin_amdgcn_mfma_f32_32x32x16_bf16(ah, bl, accB, 0, 0, 0);
    accB = __builtin_amdgcn_mfma_f32_32x32x16_bf16(al, bh, accB, 0, 0, 0);
  }
  // C/D: col(n)=lane&31 (proto), row(m)=(rg&3)+8*(rg>>2)+4*(lane>>5)
  const int h = lane >> 5;
  #pragma unroll
  for (int rg = 0; rg < 16; ++rg) {
    const int   m  = (rg & 3) + 8 * (rg >> 2) + 4 * h;
    const float dv = 0.5f * (wqk + xqs[m]) - (accA[rg] + accB[rg]);
    sout[rg] = apk * __expf(-g2k * dv);
  }
}

// ---- main: 512 blocks x 512 thr (2 blocks/CU). Block bx: samples bx*32..+32,
// ALL 512 protos. Wave wv owns tiles 2wv,2wv+1. LDS pool 64KB: A-frags 32KB
// until B2, then sc[32][512] swizzled; endgame E/R/kv alias after B4. ----
__global__ __launch_bounds__(512)
void evid32x(const float* __restrict__ X,
             const unsigned short* __restrict__ PWH, const unsigned short* __restrict__ PWL,
             const float* __restrict__ VST, const float* __restrict__ WQ,
             const float* __restrict__ AP, const float* __restrict__ G2,
             float* __restrict__ OUT)
{
  __shared__ __align__(16) char pool[65536];
  __shared__ float xqs[32];
  short* Ah = (short*)pool;            // 8192 shorts = 16KB
  short* Al = (short*)(pool + 16384);  // 8192 shorts = 16KB
  float* sc = (float*)pool;            // 32 x 512 floats = 64KB (post-B2)

  const int t    = threadIdx.x;
  const int lane = t & 63;
  const int wv   = __builtin_amdgcn_readfirstlane(t >> 6);  // wave 0..7
  const int bx   = blockIdx.x;
  const int bbase = bx * 32;
  const int pl = lane & 31, h = lane >> 5;

  // ---- stage: 32 X rows f32 -> hi/lo bf16 fragments (16 lanes/row) ----
  {
    const int r  = t >> 4;             // 0..31
    const int sg = t & 15;
    const float* xrow = X + (size_t)(bbase + r) * ND;
    float ssq = 0.f;
    #pragma unroll
    for (int it = 0; it < 4; ++it) {
      const int c0 = it * 64 + sg * 4;
      const float4 v = *(const float4*)(xrow + c0);
      const float vv[4] = {v.x, v.y, v.z, v.w};
      short4v h4, l4;
      #pragma unroll
      for (int j = 0; j < 4; ++j) {
        ssq = fmaf(vv[j], vv[j], ssq);
        const unsigned short hh = f2bf_rn(vv[j]);
        h4[j] = (short)hh;
        l4[j] = (short)f2bf_rn(vv[j] - bf2f(hh));
      }
      const int step = c0 >> 4, hf = (c0 >> 3) & 1, j0 = c0 & 7;
      const int base = (step * 64 + r + 32 * hf) * 8 + j0;
      *(short4v*)&Ah[base] = h4;
      *(short4v*)&Al[base] = l4;
    }
    ssq += __shfl_xor(ssq, 1, 64);
    ssq += __shfl_xor(ssq, 2, 64);
    ssq += __shfl_xor(ssq, 4, 64);
    ssq += __shfl_xor(ssq, 8, 64);
    if (sg == 0) xqs[r] = ssq;
  }
  __syncthreads();                     // B1: A-frags + xqs ready

  // ---- MFMA: wave wv -> tiles 2wv, 2wv+1 (same A, two B-tiles) ----
  const int kp0 = wv * 64 + pl, kp1 = kp0 + 32;
  const float wq0 = WQ[kp0], ap0 = AP[kp0], g20 = G2[kp0];
  const float wq1 = WQ[kp1], ap1 = AP[kp1], g21 = G2[kp1];
  const short8* bH0 = (const short8*)PWH + (size_t)(2 * wv) * 1024 + lane;
  const short8* bL0 = (const short8*)PWL + (size_t)(2 * wv) * 1024 + lane;

  float sreg0[16], sreg1[16];
  mfma_pass(Ah, Al, bH0, bL0, lane, xqs, wq0, ap0, g20, sreg0);
  mfma_pass(Ah, Al, bH0 + 1024, bL0 + 1024, lane, xqs, wq1, ap1, g21, sreg1);

  __syncthreads();                     // B2: all MFMA done, A-frags dead

  // write s-bands: sc[m][(p + 4m) & 511] (bijective per row -> no clobber)
  {
    const int p0 = wv * 64 + pl, p1 = p0 + 32;
    #pragma unroll
    for (int rg = 0; rg < 16; ++rg) {
      const int m = (rg & 3) + 8 * (rg >> 2) + 4 * h;
      sc[m * 512 + ((p0 + 4 * m) & 511)] = sreg0[rg];
      sc[m * 512 + ((p1 + 4 * m) & 511)] = sreg1[rg];
    }
  }
  __syncthreads();                     // B3: s-tile complete

  // ---- combine: lane = (sample pl, band h -> tile 2wv+h, protos P0..P0+31).
  // VST stream: 6 x float4 per proto (half-wave-broadcast L1 hits) into 21
  // running products. ----
  float f[OC];
  #pragma unroll
  for (int c = 0; c < OC; ++c) f[c] = 1.0f;
  {
    const int P0 = wv * 64 + h * 32;
    float sv[32];
    #pragma unroll
    for (int q = 0; q < 8; ++q)
      *(float4*)&sv[4 * q] =
        *(const float4*)&sc[pl * 512 + ((P0 + 4 * pl + 4 * q) & 511)];
    // sv[j] = s[pl][P0 + j]  (float4-safe: offsets are 4-aligned mod 512)

    const float* vrow = VST + (size_t)P0 * VSTW;
    #pragma unroll 4
    for (int j = 0; j < 32; ++j) {
      float vj[VSTW];
      #pragma unroll
      for (int q = 0; q < 6; ++q)
        *(float4*)&vj[4 * q] = *(const float4*)&vrow[j * VSTW + 4 * q];
      const float sj = sv[j];
      #pragma unroll
      for (int c = 0; c < OC; ++c) f[c] *= fmaf(-sj, vj[c], 1.0f);
    }
    // merge bands: lanes pl / pl+32 hold partials over tiles 2wv / 2wv+1
    #pragma unroll
    for (int c = 0; c < OC; ++c) f[c] *= __shfl_xor(f[c], 32, 64);
  }
  __syncthreads();                     // B4: sc reads done; pool -> endgame

  // ---- endgame: reduce 8 wave-partials, normalize, store OUT in-block ----
  float* E  = (float*)pool;            // 8*21*32 floats = 21504 B
  float* R  = (float*)(pool + 22528);  // 21*32 floats = 2688 B
  float* kv = (float*)(pool + 25216);  // 32 floats
  if (h == 0) {
    #pragma unroll
    for (int c = 0; c < OC; ++c) E[(wv * OC + c) * 32 + pl] = f[c];
  }
  __syncthreads();
  {
    const int b = t & 31, j = t >> 5;  // j = 0..15
    for (int c = j; c < OC; c += 16) {
      float p = E[c * 32 + b];
      #pragma unroll
      for (int w = 1; w < 8; ++w) p *= E[(w * OC + c) * 32 + b];
      R[c * 32 + b] = p;
    }
  }
  __syncthreads();
  if (t < 32) {
    const float Nv = R[NCLS * 32 + t];
    float K = Nv;
    #pragma unroll
    for (int c = 0; c < NCLS; ++c) K += R[c * 32 + t] - Nv;
    kv[t] = 1.0f / K;
  }
  __syncthreads();
  for (int idx = t; idx < 32 * OC; idx += 512) {
    const int b = idx / OC, c = idx - b * OC;
    const float Nv = R[NCLS * 32 + b];
    const float ik = kv[b];
    OUT[(size_t)bx * 32 * OC + idx] = (c < NCLS) ? (R[c * 32 + b] - Nv) * ik : Nv * ik;
  }
}

extern "C" void kernel_launch(void* const* d_in, const int* in_sizes, int n_in,
                              void* d_out, int out_size, void* d_ws, size_t ws_size,
                              hipStream_t stream) {
  (void)in_sizes; (void)n_in; (void)out_size; (void)ws_size;
  const float* X     = (const float*)d_in[0];
  const float* Wm    = (const float*)d_in[1];
  const float* BETA  = (const float*)d_in[2];
  const float* ALPHA = (const float*)d_in[3];
  const float* GAMMA = (const float*)d_in[4];
  float* OUT = (float*)d_out;

  char* ws = (char*)d_ws;
  unsigned short* PWH = (unsigned short*)(ws + OFF_PWH);
  unsigned short* PWL = (unsigned short*)(ws + OFF_PWL);
  float* VST = (float*)(ws + OFF_VST);
  float* WQ  = (float*)(ws + OFF_WQ);
  float* AP  = (float*)(ws + OFF_AP);
  float* G2  = (float*)(ws + OFF_G2);

  hipLaunchKernelGGL(prep, dim3(66), dim3(256), 0, stream,
                     Wm, BETA, ALPHA, GAMMA, PWH, PWL, WQ, VST, AP, G2);
  hipLaunchKernelGGL(evid32x, dim3(NBATCH / 32), dim3(512), 0, stream,
                     X, PWH, PWL, VST, WQ, AP, G2, OUT);
}

// Round 13
// 115.615 us; speedup vs baseline: 1.1240x; 1.1240x over previous
//
#include <hip/hip_runtime.h>
#include <math.h>

// EvidNets R26: R25 + FULLY-unrolled combine (fixes rule-#20 scratch spill).
//   A_c(b) = prod_k (1 - s_kb*(1-U_kc)),  N(b) = prod_k (1 - s_kb)
//   out[b][c<20] = (A_c-N)/K, out[b][20] = N/K, K = sum_c A_c - 19N
//   s_kb = alphap_k * exp(-gamma_k^2*(0.5*(|W_k|^2+|x_b|^2) - W_k.x_b))
// R25 post-mortem: structure good (2 blocks/CU, VGPR 76 allocated fine) but
// WRITE_SIZE 33.9MB vs 1.4 expected = sv[32]x4Bx512thrx512blk scratch
// round-trip: "#pragma unroll 4" left j runtime -> sv[]/vj[] runtime-indexed
// -> local memory (rule #20). Kernel 63us, VALUBusy 15%.
// R26 single change: full unroll of the 32-proto combine loop; VST row read
// as 5 explicit float4 + 1 scalar (VSTW=24 -> j*96B stays 16B-aligned).
// All indices static -> sv in 32 VGPRs, zero scratch. 21 independent
// 32-long product chains (good ILP).
// Shape recap: 512 blocks x 512 thr (2 blocks/CU, 4 waves/SIMD), block =
// 32 samples x ALL 512 protos, 64KB aliased LDS pool (A-frags -> sc ->
// endgame), full product + normalize + OUT in-block, two dispatches, no
// cross-block sync. 1024-thr blocks remain DEAD (R23/R24: 64-VGPR cap).
// NOTE: plain __launch_bounds__(512) (min-waves args spilled, R4/R8).

#define NBATCH 16384
#define ND     256
#define NP     512
#define NCLS   20
#define OC     21
#define VSTW   24                       // padded VST row width (floats)

typedef short  short8  __attribute__((ext_vector_type(8)));
typedef short  short4v __attribute__((ext_vector_type(4)));
typedef unsigned short ushort8 __attribute__((ext_vector_type(8)));
typedef float  f32x16  __attribute__((ext_vector_type(16)));

// ---- workspace layout (bytes) ----
#define OFF_PWH 0u
#define OFF_PWL 262144u
#define OFF_VST 524288u                 // float VST[512][24]: [p][c]=1-U, [p][20]=1
#define OFF_WQ  573440u
#define OFF_AP  575488u
#define OFF_G2  577536u

__device__ __forceinline__ unsigned short f2bf_rn(float f) {
  unsigned int u = __float_as_uint(f);
  unsigned int r = (u + 0x7FFFu + ((u >> 16) & 1u)) >> 16;   // RNE (finite inputs)
  return (unsigned short)r;
}
__device__ __forceinline__ float bf2f(unsigned short h) {
  return __uint_as_float(((unsigned int)h) << 16);
}

// Combined prep: blocks 0..63 pack W[512][256] -> MFMA B-fragment order hi/lo
// bf16 + row sum-squares; blocks 64..65 build VST/AP/G2 tables.
// frag elem (tile,step,lane,j) = src[tile*32+(lane&31)][step*16+8*(lane>>5)+j]
__global__ __launch_bounds__(256)
void prep(const float* __restrict__ Wsrc, const float* __restrict__ BETA,
          const float* __restrict__ alpha, const float* __restrict__ gamma,
          unsigned short* __restrict__ dh, unsigned short* __restrict__ dl,
          float* __restrict__ sq, float* __restrict__ VST,
          float* __restrict__ AP, float* __restrict__ G2)
{
  const int bid = blockIdx.x;
  if (bid < 64) {                      // ---- pack W ----
    const int tid = bid * 256 + threadIdx.x;
    const int row = tid >> 5, seg = tid & 31;
    const float4* s4 = (const float4*)(Wsrc + (size_t)row * ND + seg * 8);
    const float4 a = s4[0], b = s4[1];
    const float v[8] = {a.x, a.y, a.z, a.w, b.x, b.y, b.z, b.w};
    ushort8 hv, lv;
    float ssq = 0.f;
    #pragma unroll
    for (int j = 0; j < 8; ++j) {
      ssq = fmaf(v[j], v[j], ssq);
      const unsigned short hh = f2bf_rn(v[j]);
      hv[j] = hh;
      lv[j] = f2bf_rn(v[j] - bf2f(hh));
    }
    const int tile = row >> 5, m = row & 31, step = seg >> 1, r = seg & 1;
    const size_t cidx = (size_t)(tile * 16 + step) * 64 + m + 32 * r;
    *(ushort8*)(dh + cidx * 8) = hv;
    *(ushort8*)(dl + cidx * 8) = lv;
    #pragma unroll
    for (int off = 1; off < 32; off <<= 1) ssq += __shfl_xor(ssq, off, 64);
    if (seg == 0) sq[row] = ssq;
  } else {                             // ---- scalar tables ----
    const int k = (bid - 64) * 256 + threadIdx.x;
    if (k >= NP) return;
    float bv[NCLS], bs = 0.f;
    #pragma unroll
    for (int c = 0; c < NCLS; ++c) { bv[c] = BETA[k * NCLS + c]; bs = fmaf(bv[c], bv[c], bs); }
    const float binv = 1.f / bs;
    float* vr = VST + k * VSTW;        // transposed row: all classes of proto k
    #pragma unroll
    for (int c = 0; c < NCLS; ++c) vr[c] = 1.f - bv[c] * bv[c] * binv;
    vr[NCLS] = 1.0f;                   // class 20: U-row == 0 -> VS == 1
    vr[21] = 0.f; vr[22] = 0.f; vr[23] = 0.f;   // padding
    AP[k] = 0.99f / (1.f + __expf(-alpha[k]));
    const float g = gamma[k];
    G2[k] = g * g;
  }
}

// One MFMA pass: the block's single 32-sample A-tile vs one 32-proto B-tile.
// K=256, hi/lo split in TWO acc chains (accA = ah*bh; accB = ah*bl + al*bh),
// depth-4 B ring, epilogue s -> sout[16]. (R18b-proven body.)
__device__ __forceinline__ void mfma_pass(
    const short* __restrict__ Ah, const short* __restrict__ Al,
    const short8* __restrict__ bHc, const short8* __restrict__ bLc,
    const int lane, const float* __restrict__ xqs,
    const float wqk, const float apk, const float g2k, float* __restrict__ sout)
{
  short8 wbh[4], wbl[4];
  #pragma unroll
  for (int p = 0; p < 4; ++p) { wbh[p] = bHc[p * 64]; wbl[p] = bLc[p * 64]; }

  f32x16 accA, accB;
  #pragma unroll
  for (int i = 0; i < 16; ++i) { accA[i] = 0.f; accB[i] = 0.f; }
  const short8* aH = (const short8*)Ah + lane;
  const short8* aL = (const short8*)Al + lane;
  #pragma unroll
  for (int step = 0; step < 16; ++step) {
    const short8 ah = aH[step * 64], al = aL[step * 64];
    const short8 bh = wbh[step & 3], bl = wbl[step & 3];
    if (step < 12) {
      wbh[step & 3] = bHc[(step + 4) * 64];
      wbl[step & 3] = bLc[(step + 4) * 64];
    }
    accA = __builtin_amdgcn_mfma_f32_32x32x16_bf16(ah, bh, accA, 0, 0, 0);
    accB = __builtin_amdgcn_mfma_f32_32x32x16_bf16(ah, bl, accB, 0, 0, 0);
    accB = __builtin_amdgcn_mfma_f32_32x32x16_bf16(al, bh, accB, 0, 0, 0);
  }
  // C/D: col(n)=lane&31 (proto), row(m)=(rg&3)+8*(rg>>2)+4*(lane>>5)
  const int h = lane >> 5;
  #pragma unroll
  for (int rg = 0; rg < 16; ++rg) {
    const int   m  = (rg & 3) + 8 * (rg >> 2) + 4 * h;
    const float dv = 0.5f * (wqk + xqs[m]) - (accA[rg] + accB[rg]);
    sout[rg] = apk * __expf(-g2k * dv);
  }
}

// ---- main: 512 blocks x 512 thr (2 blocks/CU). Block bx: samples bx*32..+32,
// ALL 512 protos. Wave wv owns tiles 2wv,2wv+1. LDS pool 64KB: A-frags 32KB
// until B2, then sc[32][512] swizzled; endgame E/R/kv alias after B4. ----
__global__ __launch_bounds__(512)
void evid32x(const float* __restrict__ X,
             const unsigned short* __restrict__ PWH, const unsigned short* __restrict__ PWL,
             const float* __restrict__ VST, const float* __restrict__ WQ,
             const float* __restrict__ AP, const float* __restrict__ G2,
             float* __restrict__ OUT)
{
  __shared__ __align__(16) char pool[65536];
  __shared__ float xqs[32];
  short* Ah = (short*)pool;            // 8192 shorts = 16KB
  short* Al = (short*)(pool + 16384);  // 8192 shorts = 16KB
  float* sc = (float*)pool;            // 32 x 512 floats = 64KB (post-B2)

  const int t    = threadIdx.x;
  const int lane = t & 63;
  const int wv   = __builtin_amdgcn_readfirstlane(t >> 6);  // wave 0..7
  const int bx   = blockIdx.x;
  const int bbase = bx * 32;
  const int pl = lane & 31, h = lane >> 5;

  // ---- stage: 32 X rows f32 -> hi/lo bf16 fragments (16 lanes/row) ----
  {
    const int r  = t >> 4;             // 0..31
    const int sg = t & 15;
    const float* xrow = X + (size_t)(bbase + r) * ND;
    float ssq = 0.f;
    #pragma unroll
    for (int it = 0; it < 4; ++it) {
      const int c0 = it * 64 + sg * 4;
      const float4 v = *(const float4*)(xrow + c0);
      const float vv[4] = {v.x, v.y, v.z, v.w};
      short4v h4, l4;
      #pragma unroll
      for (int j = 0; j < 4; ++j) {
        ssq = fmaf(vv[j], vv[j], ssq);
        const unsigned short hh = f2bf_rn(vv[j]);
        h4[j] = (short)hh;
        l4[j] = (short)f2bf_rn(vv[j] - bf2f(hh));
      }
      const int step = c0 >> 4, hf = (c0 >> 3) & 1, j0 = c0 & 7;
      const int base = (step * 64 + r + 32 * hf) * 8 + j0;
      *(short4v*)&Ah[base] = h4;
      *(short4v*)&Al[base] = l4;
    }
    ssq += __shfl_xor(ssq, 1, 64);
    ssq += __shfl_xor(ssq, 2, 64);
    ssq += __shfl_xor(ssq, 4, 64);
    ssq += __shfl_xor(ssq, 8, 64);
    if (sg == 0) xqs[r] = ssq;
  }
  __syncthreads();                     // B1: A-frags + xqs ready

  // ---- MFMA: wave wv -> tiles 2wv, 2wv+1 (same A, two B-tiles) ----
  const int kp0 = wv * 64 + pl, kp1 = kp0 + 32;
  const float wq0 = WQ[kp0], ap0 = AP[kp0], g20 = G2[kp0];
  const float wq1 = WQ[kp1], ap1 = AP[kp1], g21 = G2[kp1];
  const short8* bH0 = (const short8*)PWH + (size_t)(2 * wv) * 1024 + lane;
  const short8* bL0 = (const short8*)PWL + (size_t)(2 * wv) * 1024 + lane;

  float sreg0[16], sreg1[16];
  mfma_pass(Ah, Al, bH0, bL0, lane, xqs, wq0, ap0, g20, sreg0);
  mfma_pass(Ah, Al, bH0 + 1024, bL0 + 1024, lane, xqs, wq1, ap1, g21, sreg1);

  __syncthreads();                     // B2: all MFMA done, A-frags dead

  // write s-bands: sc[m][(p + 4m) & 511] (bijective per row -> no clobber)
  {
    const int p0 = wv * 64 + pl, p1 = p0 + 32;
    #pragma unroll
    for (int rg = 0; rg < 16; ++rg) {
      const int m = (rg & 3) + 8 * (rg >> 2) + 4 * h;
      sc[m * 512 + ((p0 + 4 * m) & 511)] = sreg0[rg];
      sc[m * 512 + ((p1 + 4 * m) & 511)] = sreg1[rg];
    }
  }
  __syncthreads();                     // B3: s-tile complete

  // ---- combine: lane = (sample pl, band h -> tile 2wv+h, protos P0..P0+31).
  // FULLY unrolled: sv[] static-indexed -> registers, zero scratch. VST row
  // = 5 float4 + 1 scalar per proto (L1 half-wave broadcast). ----
  float f[OC];
  #pragma unroll
  for (int c = 0; c < OC; ++c) f[c] = 1.0f;
  {
    const int P0 = wv * 64 + h * 32;
    float sv[32];
    #pragma unroll
    for (int q = 0; q < 8; ++q)
      *(float4*)&sv[4 * q] =
        *(const float4*)&sc[pl * 512 + ((P0 + 4 * pl + 4 * q) & 511)];
    // sv[j] = s[pl][P0 + j]

    const float* vrow = VST + (size_t)P0 * VSTW;
    #pragma unroll
    for (int j = 0; j < 32; ++j) {     // FULL unroll: all indices static
      const float sj = sv[j];
      const float* vr = vrow + j * VSTW;
      const float4 v0 = *(const float4*)&vr[0];
      const float4 v1 = *(const float4*)&vr[4];
      const float4 v2 = *(const float4*)&vr[8];
      const float4 v3 = *(const float4*)&vr[12];
      const float4 v4 = *(const float4*)&vr[16];
      const float  v20 = vr[20];
      f[0]  *= fmaf(-sj, v0.x, 1.0f);
      f[1]  *= fmaf(-sj, v0.y, 1.0f);
      f[2]  *= fmaf(-sj, v0.z, 1.0f);
      f[3]  *= fmaf(-sj, v0.w, 1.0f);
      f[4]  *= fmaf(-sj, v1.x, 1.0f);
      f[5]  *= fmaf(-sj, v1.y, 1.0f);
      f[6]  *= fmaf(-sj, v1.z, 1.0f);
      f[7]  *= fmaf(-sj, v1.w, 1.0f);
      f[8]  *= fmaf(-sj, v2.x, 1.0f);
      f[9]  *= fmaf(-sj, v2.y, 1.0f);
      f[10] *= fmaf(-sj, v2.z, 1.0f);
      f[11] *= fmaf(-sj, v2.w, 1.0f);
      f[12] *= fmaf(-sj, v3.x, 1.0f);
      f[13] *= fmaf(-sj, v3.y, 1.0f);
      f[14] *= fmaf(-sj, v3.z, 1.0f);
      f[15] *= fmaf(-sj, v3.w, 1.0f);
      f[16] *= fmaf(-sj, v4.x, 1.0f);
      f[17] *= fmaf(-sj, v4.y, 1.0f);
      f[18] *= fmaf(-sj, v4.z, 1.0f);
      f[19] *= fmaf(-sj, v4.w, 1.0f);
      f[20] *= fmaf(-sj, v20, 1.0f);
    }
    // merge bands: lanes pl / pl+32 hold partials over tiles 2wv / 2wv+1
    #pragma unroll
    for (int c = 0; c < OC; ++c) f[c] *= __shfl_xor(f[c], 32, 64);
  }
  __syncthreads();                     // B4: sc reads done; pool -> endgame

  // ---- endgame: reduce 8 wave-partials, normalize, store OUT in-block ----
  float* E  = (float*)pool;            // 8*21*32 floats = 21504 B
  float* R  = (float*)(pool + 22528);  // 21*32 floats = 2688 B
  float* kv = (float*)(pool + 25216);  // 32 floats
  if (h == 0) {
    #pragma unroll
    for (int c = 0; c < OC; ++c) E[(wv * OC + c) * 32 + pl] = f[c];
  }
  __syncthreads();
  {
    const int b = t & 31, j = t >> 5;  // j = 0..15
    for (int c = j; c < OC; c += 16) {
      float p = E[c * 32 + b];
      #pragma unroll
      for (int w = 1; w < 8; ++w) p *= E[(w * OC + c) * 32 + b];
      R[c * 32 + b] = p;
    }
  }
  __syncthreads();
  if (t < 32) {
    const float Nv = R[NCLS * 32 + t];
    float K = Nv;
    #pragma unroll
    for (int c = 0; c < NCLS; ++c) K += R[c * 32 + t] - Nv;
    kv[t] = 1.0f / K;
  }
  __syncthreads();
  for (int idx = t; idx < 32 * OC; idx += 512) {
    const int b = idx / OC, c = idx - b * OC;
    const float Nv = R[NCLS * 32 + b];
    const float ik = kv[b];
    OUT[(size_t)bx * 32 * OC + idx] = (c < NCLS) ? (R[c * 32 + b] - Nv) * ik : Nv * ik;
  }
}

extern "C" void kernel_launch(void* const* d_in, const int* in_sizes, int n_in,
                              void* d_out, int out_size, void* d_ws, size_t ws_size,
                              hipStream_t stream) {
  (void)in_sizes; (void)n_in; (void)out_size; (void)ws_size;
  const float* X     = (const float*)d_in[0];
  const float* Wm    = (const float*)d_in[1];
  const float* BETA  = (const float*)d_in[2];
  const float* ALPHA = (const float*)d_in[3];
  const float* GAMMA = (const float*)d_in[4];
  float* OUT = (float*)d_out;

  char* ws = (char*)d_ws;
  unsigned short* PWH = (unsigned short*)(ws + OFF_PWH);
  unsigned short* PWL = (unsigned short*)(ws + OFF_PWL);
  float* VST = (float*)(ws + OFF_VST);
  float* WQ  = (float*)(ws + OFF_WQ);
  float* AP  = (float*)(ws + OFF_AP);
  float* G2  = (float*)(ws + OFF_G2);

  hipLaunchKernelGGL(prep, dim3(66), dim3(256), 0, stream,
                     Wm, BETA, ALPHA, GAMMA, PWH, PWL, WQ, VST, AP, G2);
  hipLaunchKernelGGL(evid32x, dim3(NBATCH / 32), dim3(512), 0, stream,
                     X, PWH, PWL, VST, WQ, AP, G2, OUT);
}